// Round 8
// baseline (1284.853 us; speedup 1.0000x reference)
//
#include <hip/hip_runtime.h>
#include <hip/hip_bf16.h>

// Problem dims
constexpr int cB = 8, cNQ = 300, cNK = 4096, cE = 256, cH = 8, cD = 32, cF = 2048, cL = 6;
constexpr int MT = cB * cNQ;    // 2400 rows of target stream
constexpr int MM = cB * cNK;    // 32768 rows of memory stream
constexpr int cQT = 10;         // q-tiles of 32
constexpr int cKS = 4;          // k-split
constexpr float kScale = 0.17677669529663687f;  // 32^-0.5
constexpr float kC2 = 0.25506601f;              // kScale * log2(e); exp2(s*kC2)=exp(s*kScale)

typedef __attribute__((ext_vector_type(8))) short short8_t;
typedef __attribute__((ext_vector_type(4))) short short4_t;
typedef __attribute__((ext_vector_type(4))) float float4_t;

__device__ inline short f2bf(float x) {
  __hip_bfloat16 h = __float2bfloat16(x);
  return __builtin_bit_cast(short, h);
}

// ---------------- init t (fp32 + bf16 mirror) ----------------
__global__ void init_t(const float* __restrict__ in, float* __restrict__ t,
                       __hip_bfloat16* __restrict__ tb, int n) {
  int i = blockIdx.x * 256 + threadIdx.x;
  if (i < n) { float v = in[i]; t[i] = v; tb[i] = __float2bfloat16(v); }
}
__global__ void cast_f32_bf16(const float* __restrict__ in, __hip_bfloat16* __restrict__ out, int n) {
  int i = blockIdx.x * 256 + threadIdx.x;
  if (i < n) out[i] = __float2bfloat16(in[i]);
}

// ---------------- transposed mask pack: mT[b][qt][key], bit j = mask[b][qt*32+j][key] ----
__global__ void pack_mask_T(const int* __restrict__ m, unsigned* __restrict__ mT) {
  int key = blockIdx.x * 256 + threadIdx.x;
  int qt = blockIdx.y, b = blockIdx.z;
  unsigned w = 0;
  for (int j = 0; j < 32; ++j) {
    int q = qt * 32 + j;
    unsigned bit = (q < cNQ) ? (unsigned)(m[((size_t)b * cNQ + q) * cNK + key] != 0) : 0u;
    w |= bit << j;
  }
  mT[((size_t)b * cQT + qt) * cNK + key] = w;
}

// ---------------- 64x64 MFMA GEMM ----------------
// EPI: 0 none, 1 relu, 2 scale-by-kC2 if n<256 (self QKV: scale Q half), 3 scale always.
// OMODE 0 row-major / 1 K head-major / 2 V transposed.
template<typename TA, typename TW, int EPI, int OMODE, typename TOUT>
__global__ __launch_bounds__(256) void gemm_mfma(const TA* __restrict__ A,
                                                 const TW* __restrict__ W,
                                                 const float* __restrict__ bias,
                                                 TOUT* __restrict__ C,
                                                 int M, int N, int K) {
  constexpr int LDSS = 72;
  __shared__ short As[64][LDSS];
  __shared__ short Ws[64][LDSS];
  int tid = threadIdx.x;
  int bm = blockIdx.x * 64, bn = blockIdx.y * 64;
  int lane = tid & 63, wave = tid >> 6;
  int m16 = lane & 15, quad = lane >> 4;
  int wm = (wave >> 1) * 32, wn = (wave & 1) * 32;

  int srow = tid >> 2;
  int kc = (tid & 3) * 16;
  bool aok = (bm + srow) < M;

  float4_t acc[2][2];
#pragma unroll
  for (int i = 0; i < 2; ++i)
#pragma unroll
    for (int j = 0; j < 2; ++j) acc[i][j] = (float4_t){0.f, 0.f, 0.f, 0.f};

  for (int k0 = 0; k0 < K; k0 += 64) {
    if constexpr (__hip_internal::is_same<TA, float>::value) {
      const float* src = A + (size_t)(bm + srow) * K + k0 + kc;
      short8_t p0, p1;
#pragma unroll
      for (int u = 0; u < 8; ++u) p0[u] = aok ? f2bf(src[u]) : (short)0;
#pragma unroll
      for (int u = 0; u < 8; ++u) p1[u] = aok ? f2bf(src[8 + u]) : (short)0;
      *(short8_t*)&As[srow][kc] = p0;
      *(short8_t*)&As[srow][kc + 8] = p1;
    } else {
      const TA* src = A + (size_t)(bm + srow) * K + k0 + kc;
      short8_t z = 0;
      *(short8_t*)&As[srow][kc] = aok ? *(const short8_t*)src : z;
      *(short8_t*)&As[srow][kc + 8] = aok ? *(const short8_t*)(src + 8) : z;
    }
    if constexpr (__hip_internal::is_same<TW, float>::value) {
      const float* src = W + (size_t)(bn + srow) * K + k0 + kc;
      short8_t p0, p1;
#pragma unroll
      for (int u = 0; u < 8; ++u) p0[u] = f2bf(src[u]);
#pragma unroll
      for (int u = 0; u < 8; ++u) p1[u] = f2bf(src[8 + u]);
      *(short8_t*)&Ws[srow][kc] = p0;
      *(short8_t*)&Ws[srow][kc + 8] = p1;
    } else {
      const TW* src = W + (size_t)(bn + srow) * K + k0 + kc;
      *(short8_t*)&Ws[srow][kc] = *(const short8_t*)src;
      *(short8_t*)&Ws[srow][kc + 8] = *(const short8_t*)(src + 8);
    }
    __syncthreads();
#pragma unroll
    for (int kk = 0; kk < 2; ++kk) {
      short8_t aF[2], bF[2];
#pragma unroll
      for (int i = 0; i < 2; ++i)
        aF[i] = *(const short8_t*)&As[wm + i * 16 + m16][kk * 32 + quad * 8];
#pragma unroll
      for (int j = 0; j < 2; ++j)
        bF[j] = *(const short8_t*)&Ws[wn + j * 16 + m16][kk * 32 + quad * 8];
#pragma unroll
      for (int i = 0; i < 2; ++i)
#pragma unroll
        for (int j = 0; j < 2; ++j)
          acc[i][j] = __builtin_amdgcn_mfma_f32_16x16x32_bf16(aF[i], bF[j], acc[i][j], 0, 0, 0);
    }
    __syncthreads();
  }

  if constexpr (OMODE == 2) {
#pragma unroll
    for (int i = 0; i < 2; ++i)
#pragma unroll
      for (int r = 0; r < 4; ++r) {
        int ml = wm + i * 16 + quad * 4 + r;
#pragma unroll
        for (int j = 0; j < 2; ++j) {
          int nl = wn + j * 16 + m16;
          Ws[nl][ml] = f2bf(acc[i][j][r] + bias[bn + nl]);
        }
      }
    __syncthreads();
    int nl = tid >> 2, mc = (tid & 3) * 16;
    if (bm + mc < M) {
      int n = bn + nl;
      __hip_bfloat16* dst = (__hip_bfloat16*)C +
          ((size_t)(n >> 5) * 32 + (n & 31)) * (size_t)M + bm + mc;
      *(short8_t*)dst = *(const short8_t*)&Ws[nl][mc];
      *(short8_t*)(dst + 8) = *(const short8_t*)&Ws[nl][mc + 8];
    }
  } else {
#pragma unroll
    for (int i = 0; i < 2; ++i) {
#pragma unroll
      for (int r = 0; r < 4; ++r) {
        int m = bm + wm + i * 16 + quad * 4 + r;
        if (m >= M) continue;
#pragma unroll
        for (int j = 0; j < 2; ++j) {
          int n = bn + wn + j * 16 + m16;
          float v = acc[i][j][r] + bias[n];
          if (EPI == 1) v = fmaxf(v, 0.f);
          if (EPI == 2 && n < 256) v *= kC2;
          if (EPI == 3) v *= kC2;
          if constexpr (OMODE == 1) {
            ((__hip_bfloat16*)C)[((size_t)(n >> 5) * M + m) * 32 + (n & 31)] = __float2bfloat16(v);
          } else if constexpr (__hip_internal::is_same<TOUT, float>::value) {
            C[(size_t)m * N + n] = v;
          } else {
            C[(size_t)m * N + n] = __float2bfloat16(v);
          }
        }
      }
    }
  }
}

// ---------------- 32x64 MFMA GEMM (CU-filling variant for M=2400 projections) --------
template<typename TW, int EPI, typename TOUT>
__global__ __launch_bounds__(256) void gemm32(const __hip_bfloat16* __restrict__ A,
                                              const TW* __restrict__ W,
                                              const float* __restrict__ bias,
                                              TOUT* __restrict__ C,
                                              int M, int N, int K) {
  __shared__ short As[32][72];
  __shared__ short Ws[64][72];
  int tid = threadIdx.x;
  int bm = blockIdx.x * 32, bn = blockIdx.y * 64;
  int lane = tid & 63, wave = tid >> 6;
  int m16 = lane & 15, quad = lane >> 4;
  int wn = wave * 16;

  int sa_row = tid >> 3, sa_c = (tid & 7) * 8;
  int sw_row = tid >> 2, sw_c = (tid & 3) * 16;
  bool aok = (bm + sa_row) < M;

  float4_t acc[2];
  acc[0] = (float4_t){0.f, 0.f, 0.f, 0.f};
  acc[1] = (float4_t){0.f, 0.f, 0.f, 0.f};

  for (int k0 = 0; k0 < K; k0 += 64) {
    {
      const __hip_bfloat16* src = A + (size_t)(bm + sa_row) * K + k0 + sa_c;
      short8_t z = 0;
      *(short8_t*)&As[sa_row][sa_c] = aok ? *(const short8_t*)src : z;
    }
    if constexpr (__hip_internal::is_same<TW, float>::value) {
      const float* src = W + (size_t)(bn + sw_row) * K + k0 + sw_c;
      short8_t p0, p1;
#pragma unroll
      for (int u = 0; u < 8; ++u) p0[u] = f2bf(src[u]);
#pragma unroll
      for (int u = 0; u < 8; ++u) p1[u] = f2bf(src[8 + u]);
      *(short8_t*)&Ws[sw_row][sw_c] = p0;
      *(short8_t*)&Ws[sw_row][sw_c + 8] = p1;
    } else {
      const TW* src = W + (size_t)(bn + sw_row) * K + k0 + sw_c;
      *(short8_t*)&Ws[sw_row][sw_c] = *(const short8_t*)src;
      *(short8_t*)&Ws[sw_row][sw_c + 8] = *(const short8_t*)(src + 8);
    }
    __syncthreads();
#pragma unroll
    for (int kk = 0; kk < 2; ++kk) {
      short8_t aF[2], bF;
#pragma unroll
      for (int i = 0; i < 2; ++i)
        aF[i] = *(const short8_t*)&As[i * 16 + m16][kk * 32 + quad * 8];
      bF = *(const short8_t*)&Ws[wn + m16][kk * 32 + quad * 8];
#pragma unroll
      for (int i = 0; i < 2; ++i)
        acc[i] = __builtin_amdgcn_mfma_f32_16x16x32_bf16(aF[i], bF, acc[i], 0, 0, 0);
    }
    __syncthreads();
  }

#pragma unroll
  for (int i = 0; i < 2; ++i) {
#pragma unroll
    for (int r = 0; r < 4; ++r) {
      int m = bm + i * 16 + quad * 4 + r;
      if (m >= M) continue;
      int n = bn + wn + m16;
      float v = acc[i][r] + bias[n];
      if (EPI == 1) v = fmaxf(v, 0.f);
      if (EPI == 3) v *= kC2;
      if constexpr (__hip_internal::is_same<TOUT, float>::value) {
        C[(size_t)m * N + n] = v;
      } else {
        C[(size_t)m * N + n] = __float2bfloat16(v);
      }
    }
  }
}

// ---------------- 128x128 MFMA GEMM (big grids: K/V proj, FFN-w1) ----------------
template<typename TW, int EPI, int OMODE, typename TOUT>
__global__ __launch_bounds__(256) void gemm128(const __hip_bfloat16* __restrict__ A,
                                               const TW* __restrict__ W,
                                               const float* __restrict__ bias,
                                               TOUT* __restrict__ C,
                                               int M, int N, int K) {
  __shared__ short lds[2 * 128 * 72];
  auto As = (short(*)[72])lds;
  auto Ws = (short(*)[72])(lds + 128 * 72);
  int tid = threadIdx.x;
  int bm = blockIdx.x * 128, bn = blockIdx.y * 128;
  int lane = tid & 63, wave = tid >> 6;
  int n16 = lane & 15, quad = lane >> 4;
  int wm = (wave >> 1) * 64, wn = (wave & 1) * 64;
  int srow = tid >> 1, kc = (tid & 1) * 32;
  bool aok = (bm + srow) < M;

  float4_t acc[4][4];
#pragma unroll
  for (int i = 0; i < 4; ++i)
#pragma unroll
    for (int j = 0; j < 4; ++j) acc[i][j] = (float4_t){0.f, 0.f, 0.f, 0.f};

  for (int k0 = 0; k0 < K; k0 += 64) {
    {
      const __hip_bfloat16* src = A + (size_t)(bm + srow) * K + k0 + kc;
      short8_t z = 0;
#pragma unroll
      for (int u = 0; u < 4; ++u)
        *(short8_t*)&As[srow][kc + u * 8] = aok ? *(const short8_t*)(src + u * 8) : z;
    }
    if constexpr (__hip_internal::is_same<TW, float>::value) {
      const float* src = W + (size_t)(bn + srow) * K + k0 + kc;
#pragma unroll
      for (int u = 0; u < 4; ++u) {
        short8_t p;
#pragma unroll
        for (int v = 0; v < 8; ++v) p[v] = f2bf(src[u * 8 + v]);
        *(short8_t*)&Ws[srow][kc + u * 8] = p;
      }
    } else {
      const TW* src = W + (size_t)(bn + srow) * K + k0 + kc;
#pragma unroll
      for (int u = 0; u < 4; ++u)
        *(short8_t*)&Ws[srow][kc + u * 8] = *(const short8_t*)(src + u * 8);
    }
    __syncthreads();
#pragma unroll
    for (int kk = 0; kk < 2; ++kk) {
      short8_t aF[4], bF[4];
#pragma unroll
      for (int i = 0; i < 4; ++i)
        aF[i] = *(const short8_t*)&As[wm + i * 16 + n16][kk * 32 + quad * 8];
#pragma unroll
      for (int j = 0; j < 4; ++j)
        bF[j] = *(const short8_t*)&Ws[wn + j * 16 + n16][kk * 32 + quad * 8];
#pragma unroll
      for (int i = 0; i < 4; ++i)
#pragma unroll
        for (int j = 0; j < 4; ++j)
          acc[i][j] = __builtin_amdgcn_mfma_f32_16x16x32_bf16(aF[i], bF[j], acc[i][j], 0, 0, 0);
    }
    __syncthreads();
  }

  if constexpr (OMODE == 2) {
    auto TT = (short(*)[128])lds;
#pragma unroll
    for (int i = 0; i < 4; ++i)
#pragma unroll
      for (int r = 0; r < 4; ++r) {
        int ml = wm + i * 16 + quad * 4 + r;
#pragma unroll
        for (int j = 0; j < 4; ++j) {
          int nl = wn + j * 16 + n16;
          TT[nl][ml] = f2bf(acc[i][j][r] + bias[bn + nl]);
        }
      }
    __syncthreads();
    int nl = tid >> 1, mh = (tid & 1) * 64;
    int n = bn + nl;
    __hip_bfloat16* dst = (__hip_bfloat16*)C +
        ((size_t)(n >> 5) * 32 + (n & 31)) * (size_t)M + bm + mh;
#pragma unroll
    for (int ch = 0; ch < 8; ++ch) {
      if (bm + mh + ch * 8 < M)
        *(short8_t*)(dst + ch * 8) = *(const short8_t*)&TT[nl][mh + ch * 8];
    }
  } else {
#pragma unroll
    for (int i = 0; i < 4; ++i) {
#pragma unroll
      for (int r = 0; r < 4; ++r) {
        int m = bm + wm + i * 16 + quad * 4 + r;
        if (m >= M) continue;
#pragma unroll
        for (int j = 0; j < 4; ++j) {
          int n = bn + wn + j * 16 + n16;
          float v = acc[i][j][r] + bias[n];
          if (EPI == 1) v = fmaxf(v, 0.f);
          if constexpr (OMODE == 1) {
            ((__hip_bfloat16*)C)[((size_t)(n >> 5) * M + m) * 32 + (n & 31)] = __float2bfloat16(v);
          } else if constexpr (__hip_internal::is_same<TOUT, float>::value) {
            C[(size_t)m * N + n] = v;
          } else {
            C[(size_t)m * N + n] = __float2bfloat16(v);
          }
        }
      }
    }
  }
}

// ---------------- cross attention, Q-shared: one block per (hb, ks) ----------------
// 4 waves; wave w owns q-tiles {w, w+4, w+8(<10)}. The block's 1024-key chunk is
// staged once into LDS (64-key double-buffered windows, T14 issue-early/write-late)
// and shared by all waves -> K/V global traffic 10x lower than per-q-tile blocks.
// Q pre-scaled by kC2 (log2 domain). No cross-wave reduction needed.
__global__ __launch_bounds__(256) void attn_cross(
    const __hip_bfloat16* __restrict__ qb,   // [B][NQ][E], head h at col h*32
    const __hip_bfloat16* __restrict__ kb,   // [H][MM][32]
    const __hip_bfloat16* __restrict__ vt,   // [H][32][MM]
    const unsigned* __restrict__ mT,         // [B][QT][NK]
    float* __restrict__ pO,                  // [ks][MT][256]
    float* __restrict__ pL) {                // [ks][64*320]
  int hb = blockIdx.x, ks = blockIdx.z;
  int h = hb & 7, bz = hb >> 3;
  const __hip_bfloat16* Q = qb + (size_t)(bz * cNQ) * cE + h * cD;
  const __hip_bfloat16* K = kb + ((size_t)h * MM + (size_t)bz * cNK) * cD;
  const __hip_bfloat16* V = vt + (size_t)h * cD * MM + (size_t)bz * cNK;
  const unsigned* mb = mT + (size_t)bz * (cQT * cNK);

  int tid = threadIdx.x;
  int lane = tid & 63, wave = tid >> 6;
  int n16 = lane & 15, quad = lane >> 4;

  __shared__ short Ks[2][64][40];   // 64 keys x 32 d (pad 40: 16B-aligned rows)
  __shared__ short Vs[2][32][72];   // 32 d x 64 keys (pad 72: 16B-aligned rows)
  __shared__ short sPa[4][32][40];  // per-wave P staging
  short* sPw = &sPa[wave][0][0];

  int nt = (wave < 2) ? 3 : 2;      // tiles 8,9 only on waves 0,1

  short8_t qf[3][2];
#pragma unroll
  for (int t = 0; t < 3; ++t) {
    int qtt = wave + t * 4;
#pragma unroll
    for (int qi = 0; qi < 2; ++qi) {
      qf[t][qi] = 0;
      int qr = qtt * 32 + qi * 16 + n16;
      if (t < nt && qr < cNQ)
        qf[t][qi] = *(const short8_t*)(Q + (size_t)qr * cE + quad * 8);
    }
  }
  short8_t ones;
#pragma unroll
  for (int j = 0; j < 8; ++j) ones[j] = f2bf(1.0f);

  float4_t accO[3][2][2];
  float4_t accL[3][2];
#pragma unroll
  for (int t = 0; t < 3; ++t)
#pragma unroll
    for (int qi = 0; qi < 2; ++qi) {
      accL[t][qi] = (float4_t){0.f, 0.f, 0.f, 0.f};
#pragma unroll
      for (int di = 0; di < 2; ++di) accO[t][qi][di] = (float4_t){0.f, 0.f, 0.f, 0.f};
    }
  float4_t zero4 = {0.f, 0.f, 0.f, 0.f};

  constexpr int CHUNK = cNK / cKS;          // 1024
  constexpr int NW = CHUNK / 64;            // 16 windows
  int kbeg = ks * CHUNK;

  int krow = tid >> 2, kcol = (tid & 3) * 8;
  int vrow = tid >> 3, vcol = (tid & 7) * 8;
  short8_t kreg, vreg;

#define CX_LDG(KO)                                                            \
  {                                                                           \
    kreg = *(const short8_t*)(K + (size_t)((KO) + krow) * cD + kcol);         \
    vreg = *(const short8_t*)(V + (size_t)vrow * MM + (KO) + vcol);           \
  }
#define CX_STO(BUF)                                                           \
  {                                                                           \
    *(short8_t*)&Ks[BUF][krow][kcol] = kreg;                                  \
    *(short8_t*)&Vs[BUF][vrow][vcol] = vreg;                                  \
  }

  CX_LDG(kbeg);
  CX_STO(0);
  __syncthreads();

  for (int w = 0; w < NW; ++w) {
    int cur = w & 1;
    if (w + 1 < NW) CX_LDG(kbeg + (w + 1) * 64);   // issue early (T14)
#pragma unroll
    for (int s = 0; s < 2; ++s) {
      short8_t kf0 = *(const short8_t*)&Ks[cur][s * 32 + 2 * n16][quad * 8];
      short8_t kf1 = *(const short8_t*)&Ks[cur][s * 32 + 2 * n16 + 1][quad * 8];
      short8_t vf0 = *(const short8_t*)&Vs[cur][n16][s * 32 + quad * 8];
      short8_t vf1 = *(const short8_t*)&Vs[cur][16 + n16][s * 32 + quad * 8];
      int kabs = kbeg + w * 64 + s * 32 + 2 * n16;
#pragma unroll
      for (int t = 0; t < 3; ++t) {
        if (t >= nt) continue;
        int qtt = wave + t * 4;
        uint2 mw = *(const uint2*)(mb + (size_t)qtt * cNK + kabs);
        float4_t s00 = __builtin_amdgcn_mfma_f32_16x16x32_bf16(qf[t][0], kf0, zero4, 0, 0, 0);
        float4_t s01 = __builtin_amdgcn_mfma_f32_16x16x32_bf16(qf[t][0], kf1, zero4, 0, 0, 0);
        float4_t s10 = __builtin_amdgcn_mfma_f32_16x16x32_bf16(qf[t][1], kf0, zero4, 0, 0, 0);
        float4_t s11 = __builtin_amdgcn_mfma_f32_16x16x32_bf16(qf[t][1], kf1, zero4, 0, 0, 0);
#pragma unroll
        for (int qi = 0; qi < 2; ++qi) {
          const float4_t& sa = qi ? s10 : s00;
          const float4_t& sb = qi ? s11 : s01;
#pragma unroll
          for (int r = 0; r < 4; ++r) {
            int row = qi * 16 + quad * 4 + r;
            float e0, e1;
            asm("v_exp_f32 %0, %1" : "=v"(e0) : "v"(sa[r]));
            asm("v_exp_f32 %0, %1" : "=v"(e1) : "v"(sb[r]));
            e0 *= (float)((mw.x >> row) & 1u);
            e1 *= (float)((mw.y >> row) & 1u);
            unsigned pw;
            asm("v_cvt_pk_bf16_f32 %0, %1, %2" : "=v"(pw) : "v"(e0), "v"(e1));
            *(unsigned*)&sPw[row * 40 + 2 * n16] = pw;
          }
        }
#pragma unroll
        for (int qi = 0; qi < 2; ++qi) {
          short8_t pf = *(const short8_t*)&sPw[(qi * 16 + n16) * 40 + quad * 8];
          accO[t][qi][0] = __builtin_amdgcn_mfma_f32_16x16x32_bf16(pf, vf0, accO[t][qi][0], 0, 0, 0);
          accO[t][qi][1] = __builtin_amdgcn_mfma_f32_16x16x32_bf16(pf, vf1, accO[t][qi][1], 0, 0, 0);
          accL[t][qi]    = __builtin_amdgcn_mfma_f32_16x16x32_bf16(pf, ones, accL[t][qi], 0, 0, 0);
        }
      }
    }
    if (w + 1 < NW) CX_STO((w + 1) & 1);   // write late (waits vmcnt internally)
    __syncthreads();
  }
#undef CX_LDG
#undef CX_STO

  size_t oBase = (size_t)ks * ((size_t)MT * 256) + (size_t)(bz * cNQ) * 256 + h * 32;
#pragma unroll
  for (int t = 0; t < 3; ++t) {
    if (t >= nt) continue;
    int qtt = wave + t * 4;
#pragma unroll
    for (int qi = 0; qi < 2; ++qi) {
#pragma unroll
      for (int r = 0; r < 4; ++r) {
        int row = qtt * 32 + qi * 16 + quad * 4 + r;
        if (row < cNQ) {
          pO[oBase + (size_t)row * 256 + n16]      = accO[t][qi][0][r];
          pO[oBase + (size_t)row * 256 + 16 + n16] = accO[t][qi][1][r];
          if (n16 == 0)
            pL[(size_t)ks * (64 * 320) + (size_t)hb * 320 + row] = accL[t][qi][r];
        }
      }
    }
  }
}

// ---------------- flash attention (self + fallback): 4 waves per (hb,qt,ks) ---------
// Q pre-scaled by kC2; softmax numerator = raw v_exp_f32. Ping-pong register prefetch.
template<typename TQ, bool MASKED, bool SPLIT>
__global__ __launch_bounds__(256) void attn_flash(
    const TQ* __restrict__ qb, size_t strQb, size_t strQh, int qRowStr,
    const __hip_bfloat16* __restrict__ kb, size_t strKb, size_t strKh, int kRowStr,
    const __hip_bfloat16* __restrict__ vt, size_t strVb, size_t strVh, size_t strVd,
    const unsigned* __restrict__ mT, size_t strMb,
    float* __restrict__ pO, size_t pStrO,
    float* __restrict__ pL, size_t pStrL,
    __hip_bfloat16* __restrict__ outF,
    int nq, int nk, int kChunk) {
  int hb = blockIdx.x;
  int h = hb & 7, bz = hb >> 3;
  int qt = blockIdx.y, ks = blockIdx.z;
  int qbase = qt * 32;

  const TQ* q = qb + (size_t)bz * strQb + (size_t)h * strQh;
  const __hip_bfloat16* K = kb + (size_t)bz * strKb + (size_t)h * strKh;
  const __hip_bfloat16* V = vt + (size_t)bz * strVb + (size_t)h * strVh;
  const unsigned* mrow = MASKED ? (mT + (size_t)bz * strMb + (size_t)qt * cNK) : nullptr;

  int tid = threadIdx.x;
  int lane = tid & 63, wave = tid >> 6;
  int n16 = lane & 15, quad = lane >> 4;

  __shared__ float redO[4][32][33];
  __shared__ float redL[4][32];
  short* sPw = (short*)&redO[0][0][0] + wave * (32 * 40);

  short8_t qf[2];
#pragma unroll
  for (int qi = 0; qi < 2; ++qi) {
    qf[qi] = 0;
    int qr = qbase + qi * 16 + n16;
    if (qr < nq) {
      const TQ* qp = q + (size_t)qr * qRowStr + quad * 8;
      if constexpr (__hip_internal::is_same<TQ, float>::value) {
#pragma unroll
        for (int j = 0; j < 8; ++j) qf[qi][j] = f2bf(qp[j]);
      } else {
        qf[qi] = *(const short8_t*)qp;
      }
    }
  }
  short8_t ones;
#pragma unroll
  for (int j = 0; j < 8; ++j) ones[j] = f2bf(1.0f);

  float4_t accO[2][2], accL[2];
#pragma unroll
  for (int qi = 0; qi < 2; ++qi) {
    accL[qi] = (float4_t){0.f, 0.f, 0.f, 0.f};
#pragma unroll
    for (int di = 0; di < 2; ++di) accO[qi][di] = (float4_t){0.f, 0.f, 0.f, 0.f};
  }
  float4_t zero4 = {0.f, 0.f, 0.f, 0.f};

  int kpad = (nk + 31) & ~31;
  int kbeg = ks * kChunk + wave * 32;
  int kend = ks * kChunk + kChunk;
  if (kend > kpad) kend = kpad;

  short8_t ka0, ka1, va0, va1, kb0, kb1, vb0, vb1;
  unsigned wa0 = 0, wa1 = 0, wb0 = 0, wb1 = 0;
  float oa0 = 1.f, oa1 = 1.f, ob0 = 1.f, ob1 = 1.f;

#define ATTN_LOAD(KF0, KF1, VF0, VF1, W0, W1, O0, O1, KO)                          \
  {                                                                                \
    int k0_ = (KO) + 2 * n16;                                                      \
    if (MASKED) {                                                                  \
      uint2 mw_ = *(const uint2*)(mrow + k0_);                                     \
      W0 = mw_.x; W1 = mw_.y;                                                      \
    } else {                                                                       \
      O0 = (k0_ < nk) ? 1.f : 0.f;                                                 \
      O1 = (k0_ + 1 < nk) ? 1.f : 0.f;                                             \
    }                                                                              \
    KF0 = *(const short8_t*)(K + (size_t)k0_ * kRowStr + quad * 8);                \
    KF1 = *(const short8_t*)(K + (size_t)(k0_ + 1) * kRowStr + quad * 8);          \
    VF0 = *(const short8_t*)(V + (size_t)n16 * strVd + (KO) + quad * 8);           \
    VF1 = *(const short8_t*)(V + (size_t)(16 + n16) * strVd + (KO) + quad * 8);    \
  }

#define ATTN_COMPUTE(CK0, CK1, CV0, CV1, CW0, CW1, CO0, CO1)                       \
  {                                                                                \
    float4_t s00 = __builtin_amdgcn_mfma_f32_16x16x32_bf16(qf[0], CK0, zero4, 0, 0, 0); \
    float4_t s01 = __builtin_amdgcn_mfma_f32_16x16x32_bf16(qf[0], CK1, zero4, 0, 0, 0); \
    float4_t s10 = __builtin_amdgcn_mfma_f32_16x16x32_bf16(qf[1], CK0, zero4, 0, 0, 0); \
    float4_t s11 = __builtin_amdgcn_mfma_f32_16x16x32_bf16(qf[1], CK1, zero4, 0, 0, 0); \
    _Pragma("unroll")                                                              \
    for (int qi = 0; qi < 2; ++qi) {                                               \
      const float4_t& sa = qi ? s10 : s00;                                         \
      const float4_t& sb = qi ? s11 : s01;                                         \
      _Pragma("unroll")                                                            \
      for (int r = 0; r < 4; ++r) {                                                \
        int row_ = qi * 16 + quad * 4 + r;                                         \
        float e0_, e1_;                                                            \
        asm("v_exp_f32 %0, %1" : "=v"(e0_) : "v"(sa[r]));                          \
        asm("v_exp_f32 %0, %1" : "=v"(e1_) : "v"(sb[r]));                          \
        float m0_, m1_;                                                            \
        if (MASKED) {                                                              \
          m0_ = (float)((CW0 >> row_) & 1u);                                       \
          m1_ = (float)((CW1 >> row_) & 1u);                                       \
        } else {                                                                   \
          m0_ = CO0; m1_ = CO1;                                                    \
        }                                                                          \
        e0_ *= m0_; e1_ *= m1_;                                                    \
        unsigned pw_;                                                              \
        asm("v_cvt_pk_bf16_f32 %0, %1, %2" : "=v"(pw_) : "v"(e0_), "v"(e1_));      \
        *(unsigned*)&sPw[row_ * 40 + 2 * n16] = pw_;                               \
      }                                                                            \
    }                                                                              \
    _Pragma("unroll")                                                              \
    for (int qi = 0; qi < 2; ++qi) {                                               \
      short8_t pf = *(const short8_t*)&sPw[(qi * 16 + n16) * 40 + quad * 8];       \
      accO[qi][0] = __builtin_amdgcn_mfma_f32_16x16x32_bf16(pf, CV0, accO[qi][0], 0, 0, 0); \
      accO[qi][1] = __builtin_amdgcn_mfma_f32_16x16x32_bf16(pf, CV1, accO[qi][1], 0, 0, 0); \
      accL[qi]    = __builtin_amdgcn_mfma_f32_16x16x32_bf16(pf, ones, accL[qi], 0, 0, 0);   \
    }                                                                              \
  }

  int ko = kbeg;
  if (ko < kend) {
    ATTN_LOAD(ka0, ka1, va0, va1, wa0, wa1, oa0, oa1, ko);
    while (true) {
      int nx = ko + 128;
      if (nx < kend) ATTN_LOAD(kb0, kb1, vb0, vb1, wb0, wb1, ob0, ob1, nx);
      ATTN_COMPUTE(ka0, ka1, va0, va1, wa0, wa1, oa0, oa1);
      ko = nx;
      if (ko >= kend) break;
      nx = ko + 128;
      if (nx < kend) ATTN_LOAD(ka0, ka1, va0, va1, wa0, wa1, oa0, oa1, nx);
      ATTN_COMPUTE(kb0, kb1, vb0, vb1, wb0, wb1, ob0, ob1);
      ko = nx;
      if (ko >= kend) break;
    }
  }
#undef ATTN_LOAD
#undef ATTN_COMPUTE

  __syncthreads();
#pragma unroll
  for (int qi = 0; qi < 2; ++qi) {
#pragma unroll
    for (int r = 0; r < 4; ++r) {
      int row = qi * 16 + quad * 4 + r;
#pragma unroll
      for (int di = 0; di < 2; ++di)
        redO[wave][row][di * 16 + n16] = accO[qi][di][r];
      if (n16 == 0) redL[wave][row] = accL[qi][r];
    }
  }
  __syncthreads();

  int row = tid >> 3, c0 = (tid & 7) * 4;
  if constexpr (SPLIT) {
    size_t oBase = (size_t)ks * pStrO + (size_t)(bz * cNQ) * 256 + h * 32;
    if (qbase + row < nq) {
      float4_t o;
#pragma unroll
      for (int u = 0; u < 4; ++u)
        o[u] = redO[0][row][c0 + u] + redO[1][row][c0 + u] +
               redO[2][row][c0 + u] + redO[3][row][c0 + u];
      *(float4_t*)&pO[oBase + (size_t)(qbase + row) * 256 + c0] = o;
    }
    if (tid < 32 && qbase + tid < nq) {
      float l = redL[0][tid] + redL[1][tid] + redL[2][tid] + redL[3][tid];
      pL[(size_t)ks * pStrL + (size_t)hb * 320 + qbase + tid] = l;
    }
  } else {
    if (qbase + row < nq) {
      float l = redL[0][row] + redL[1][row] + redL[2][row] + redL[3][row];
      float inv = 1.f / l;
      float o[4];
#pragma unroll
      for (int u = 0; u < 4; ++u)
        o[u] = (redO[0][row][c0 + u] + redO[1][row][c0 + u] +
                redO[2][row][c0 + u] + redO[3][row][c0 + u]) * inv;
      short4_t res = {f2bf(o[0]), f2bf(o[1]), f2bf(o[2]), f2bf(o[3])};
      *(short4_t*)&outF[(size_t)(bz * cNQ + qbase + row) * 256 + h * 32 + c0] = res;
    }
  }
}

// ---------------- merge k-split partials -> bf16 ----------------
__global__ __launch_bounds__(64) void attn_merge(const float* __restrict__ pO,
                                                 const float* __restrict__ pL,
                                                 __hip_bfloat16* __restrict__ out) {
  int row = blockIdx.x;
  int lane = threadIdx.x;
  int c0 = lane * 4;
  int bz = row / cNQ, qq = row - bz * cNQ;
  int h = c0 >> 5;
  float l = 0.f;
#pragma unroll
  for (int ks = 0; ks < cKS; ++ks)
    l += pL[(size_t)ks * (64 * 320) + (size_t)(bz * 8 + h) * 320 + qq];
  float inv = 1.f / l;
  float o[4] = {0.f, 0.f, 0.f, 0.f};
#pragma unroll
  for (int ks = 0; ks < cKS; ++ks) {
    const float4_t v = *(const float4_t*)&pO[(size_t)ks * (MT * 256) + (size_t)row * 256 + c0];
#pragma unroll
    for (int u = 0; u < 4; ++u) o[u] += v[u];
  }
  short4_t res = {f2bf(o[0] * inv), f2bf(o[1] * inv), f2bf(o[2] * inv), f2bf(o[3] * inv)};
  *(short4_t*)&out[(size_t)row * 256 + c0] = res;
}

// ---------------- residual + LayerNorm (fp32 t + bf16 mirror), one wave per row ------
__global__ __launch_bounds__(64) void add_ln_k(float* __restrict__ t,
                                               __hip_bfloat16* __restrict__ tb,
                                               const float* __restrict__ delta,
                                               const float* __restrict__ g,
                                               const float* __restrict__ bb) {
  int r = blockIdx.x, lane = threadIdx.x;
  size_t base = (size_t)r * cE + lane * 4;
  float x[4];
  float s = 0.f;
#pragma unroll
  for (int i = 0; i < 4; ++i) { x[i] = t[base + i] + delta[base + i]; s += x[i]; }
  for (int off = 32; off; off >>= 1) s += __shfl_xor(s, off);
  float mean = s * (1.f / cE);
  float v = 0.f;
#pragma unroll
  for (int i = 0; i < 4; ++i) { float dd = x[i] - mean; v += dd * dd; }
  for (int off = 32; off; off >>= 1) v += __shfl_xor(v, off);
  float rstd = rsqrtf(v * (1.f / cE) + 1e-5f);
  float y[4];
#pragma unroll
  for (int i = 0; i < 4; ++i) {
    y[i] = (x[i] - mean) * rstd * g[lane * 4 + i] + bb[lane * 4 + i];
    t[base + i] = y[i];
  }
  short4_t pb = {f2bf(y[0]), f2bf(y[1]), f2bf(y[2]), f2bf(y[3])};
  *(short4_t*)&tb[base] = pb;
}

// ---------------- final LayerNorm -> fp32 out ----------------
__global__ __launch_bounds__(64) void final_ln_k(const float* __restrict__ t,
                                                 const float* __restrict__ g,
                                                 const float* __restrict__ bb,
                                                 float* __restrict__ out) {
  int r = blockIdx.x, lane = threadIdx.x;
  size_t base = (size_t)r * cE + lane * 4;
  float x[4];
  float s = 0.f;
#pragma unroll
  for (int i = 0; i < 4; ++i) { x[i] = t[base + i]; s += x[i]; }
  for (int off = 32; off; off >>= 1) s += __shfl_xor(s, off);
  float mean = s * (1.f / cE);
  float v = 0.f;
#pragma unroll
  for (int i = 0; i < 4; ++i) { float dd = x[i] - mean; v += dd * dd; }
  for (int off = 32; off; off >>= 1) v += __shfl_xor(v, off);
  float rstd = rsqrtf(v * (1.f / cE) + 1e-5f);
#pragma unroll
  for (int i = 0; i < 4; ++i)
    out[base + i] = (x[i] - mean) * rstd * g[lane * 4 + i] + bb[lane * 4 + i];
}

// ---------------- pipeline (templated on weight dtype TW) ----------------
struct Bufs {
  float *t, *s1, *s2, *pO, *pL;
  __hip_bfloat16 *tb, *big2, *vtq, *saOut, *s2b, *qbf, *ffnh, *kbuf, *vtb, *membf;
  unsigned* mTr;
  const float* memory;
  bool fullKV, precast;
};

template<typename TW>
static void run_layers(const TW* const* wt, const float* const* bs,
                       const float* ln1g, const float* ln1b,
                       const float* ln2g, const float* ln2b,
                       const float* ln3g, const float* ln3b,
                       Bufs B, hipStream_t stream) {
  const size_t pStrO = (size_t)MT * 256, pStrL = 64 * 320;
  for (int l = 0; l < cL; ++l) {
    const TW* wqkv = wt[0] + (size_t)l * 3 * cE * cE;  const float* bqkv = bs[0] + (size_t)l * 3 * cE;
    const TW* wo   = wt[1] + (size_t)l * cE * cE;      const float* bo   = bs[1] + (size_t)l * cE;
    const TW* wq   = wt[2] + (size_t)l * cE * cE;      const float* bq   = bs[2] + (size_t)l * cE;
    const TW* wk   = wt[3] + (size_t)l * cE * cE;      const float* bk   = bs[3] + (size_t)l * cE;
    const TW* wv   = wt[4] + (size_t)l * cE * cE;      const float* bv   = bs[4] + (size_t)l * cE;
    const TW* wco  = wt[5] + (size_t)l * cE * cE;      const float* bco  = bs[5] + (size_t)l * cE;
    const TW* w1   = wt[6] + (size_t)l * cF * cE;      const float* b1   = bs[6] + (size_t)l * cF;
    const TW* w2   = wt[7] + (size_t)l * cE * cF;      const float* b2   = bs[7] + (size_t)l * cE;

    // 1) self Q|K -> big2 (bf16, stride 512); Q half (n<256) pre-scaled by kC2
    gemm_mfma<__hip_bfloat16, TW, 2, 0, __hip_bfloat16><<<dim3(38, 8), 256, 0, stream>>>(
        B.tb, wqkv, bqkv, B.big2, MT, 512, cE);
    // 2) self V^T -> vtq [h][dim][2400]
    gemm_mfma<__hip_bfloat16, TW, 0, 2, __hip_bfloat16><<<dim3(38, 4), 256, 0, stream>>>(
        B.tb, wqkv + (size_t)512 * cE, bqkv + 512, B.vtq, MT, cE, cE);
    // 3) self flash, no k-split; normalized bf16 out -> saOut. Merge eliminated.
    attn_flash<__hip_bfloat16, false, false><<<dim3(64, cQT, 1), 256, 0, stream>>>(
        B.big2, (size_t)cNQ * 512, 32, 512,
        B.big2 + 256, (size_t)cNQ * 512, 32, 512,
        B.vtq, 300, (size_t)cD * MT, MT,
        nullptr, 0,
        B.pO, pStrO, B.pL, pStrL, B.saOut, cNQ, cNQ, 320);
    // 4) sa out proj -> s2 (fp32)
    gemm32<TW, 0, float><<<dim3(75, 4), 256, 0, stream>>>(
        B.saOut, wo, bo, B.s2, MT, cE, cE);
    add_ln_k<<<MT, 64, 0, stream>>>(B.t, B.tb, B.s2, ln1g + (size_t)l * cE, ln1b + (size_t)l * cE);
    // 5) q proj -> qbf (pre-scaled by kC2)
    gemm32<TW, 3, __hip_bfloat16><<<dim3(75, 4), 256, 0, stream>>>(
        B.tb, wq, bq, B.qbf, MT, cE, cE);
    // 6) K/V projections + cross attention (Q-shared, K/V LDS-staged)
    if (B.fullKV && B.precast) {
      gemm128<TW, 0, 1, __hip_bfloat16><<<dim3(256, 2), 256, 0, stream>>>(
          B.membf, wk, bk, B.kbuf, MM, cE, cE);
      gemm128<TW, 0, 2, __hip_bfloat16><<<dim3(256, 2), 256, 0, stream>>>(
          B.membf, wv, bv, B.vtb, MM, cE, cE);
      attn_cross<<<dim3(64, 1, cKS), 256, 0, stream>>>(
          B.qbf, B.kbuf, B.vtb, B.mTr, B.pO, B.pL);
      attn_merge<<<MT, 64, 0, stream>>>(B.pO, B.pL, B.s2b);
    } else {
      for (int b = 0; b < cB; ++b) {
        const float* memb = B.memory + (size_t)b * cNK * cE;
        gemm_mfma<float, TW, 0, 1, __hip_bfloat16><<<dim3(64, 4), 256, 0, stream>>>(
            memb, wk, bk, B.kbuf, cNK, cE, cE);
        gemm_mfma<float, TW, 0, 2, __hip_bfloat16><<<dim3(64, 4), 256, 0, stream>>>(
            memb, wv, bv, B.vtb, cNK, cE, cE);
        attn_flash<__hip_bfloat16, true, true><<<dim3(8, cQT, cKS), 256, 0, stream>>>(
            B.qbf + (size_t)b * cNQ * cE, 0, 32, cE,
            B.kbuf, 0, (size_t)cNK * cD, cD,
            B.vtb, 0, (size_t)cD * cNK, cNK,
            B.mTr + (size_t)b * cQT * cNK, 0,
            B.pO + (size_t)b * cNQ * 256, pStrO, B.pL + (size_t)b * 8 * 320, pStrL,
            nullptr, cNQ, cNK, 1024);
      }
      attn_merge<<<MT, 64, 0, stream>>>(B.pO, B.pL, B.s2b);
    }
    // 7) ca out proj -> s1 (fp32)
    gemm32<TW, 0, float><<<dim3(75, 4), 256, 0, stream>>>(
        B.s2b, wco, bco, B.s1, MT, cE, cE);
    add_ln_k<<<MT, 64, 0, stream>>>(B.t, B.tb, B.s1, ln2g + (size_t)l * cE, ln2b + (size_t)l * cE);
    // 8) FFN
    gemm128<TW, 1, 0, __hip_bfloat16><<<dim3(19, 16), 256, 0, stream>>>(
        B.tb, w1, b1, B.ffnh, MT, cF, cE);
    gemm32<TW, 0, float><<<dim3(75, 4), 256, 0, stream>>>(
        B.ffnh, w2, b2, B.s1, MT, cE, cF);
    add_ln_k<<<MT, 64, 0, stream>>>(B.t, B.tb, B.s1, ln3g + (size_t)l * cE, ln3b + (size_t)l * cE);
  }
}

extern "C" void kernel_launch(void* const* d_in, const int* in_sizes, int n_in,
                              void* d_out, int out_size, void* d_ws, size_t ws_size,
                              hipStream_t stream) {
  (void)in_sizes; (void)n_in; (void)out_size;
  const float* tgt    = (const float*)d_in[0];
  const float* memory = (const float*)d_in[1];
  const int*   gmask  = (const int*)d_in[2];
  const float* w_in[8]  = {(const float*)d_in[3], (const float*)d_in[5], (const float*)d_in[7],
                           (const float*)d_in[9], (const float*)d_in[11], (const float*)d_in[13],
                           (const float*)d_in[15], (const float*)d_in[17]};
  const float* b_in[8]  = {(const float*)d_in[4], (const float*)d_in[6], (const float*)d_in[8],
                           (const float*)d_in[10], (const float*)d_in[12], (const float*)d_in[14],
                           (const float*)d_in[16], (const float*)d_in[18]};
  const size_t w_sz[8]  = {(size_t)cL*3*cE*cE, (size_t)cL*cE*cE, (size_t)cL*cE*cE,
                           (size_t)cL*cE*cE, (size_t)cL*cE*cE, (size_t)cL*cE*cE,
                           (size_t)cL*cF*cE, (size_t)cL*cE*cF};
  const float* ln1g = (const float*)d_in[19], *ln1b = (const float*)d_in[20];
  const float* ln2g = (const float*)d_in[21], *ln2b = (const float*)d_in[22];
  const float* ln3g = (const float*)d_in[23], *ln3b = (const float*)d_in[24];
  const float* lnfg = (const float*)d_in[25], *lnfb = (const float*)d_in[26];

  // ---- workspace allocator (256B aligned), ordered by value ----
  char* wp = (char*)d_ws;
  auto alloc = [&](size_t bytes) { void* p = wp; wp += (bytes + 255) & ~(size_t)255; return p; };

  Bufs B;
  B.memory = memory;
  B.t  = (float*)alloc((size_t)MT * cE * 4);
  B.s1 = (float*)alloc((size_t)MT * cE * 4);
  B.s2 = (float*)alloc((size_t)MT * cE * 4);
  B.tb = (__hip_bfloat16*)alloc((size_t)MT * cE * 2);
  B.big2 = (__hip_bfloat16*)alloc((size_t)MT * 512 * 2);
  B.vtq  = (__hip_bfloat16*)alloc((size_t)cH * cD * MT * 2);
  B.mTr = (unsigned*)alloc((size_t)cB * cQT * cNK * 4);
  B.pO = (float*)alloc((size_t)cKS * MT * 256 * 4);
  B.pL = (float*)alloc((size_t)cKS * 64 * 320 * 4);
  B.saOut = (__hip_bfloat16*)B.pO;                 // self-attn bf16 out (pO free then)
  B.s2b = B.big2 + (size_t)MT * 256;               // alias (big2 upper half, free after self)
  B.qbf = (__hip_bfloat16*)B.s1;                   // alias (s1 fp32 written later)
  B.ffnh = (__hip_bfloat16*)B.pO;                  // alias (pO free during FFN)

  size_t kvFull = (size_t)cH * MM * cD * 2;        // 16.78 MB each
  size_t used = (size_t)(wp - (char*)d_ws);
  B.fullKV = ws_size >= used + 2 * kvFull;
  if (B.fullKV) {
    B.kbuf = (__hip_bfloat16*)alloc(kvFull);
    B.vtb  = (__hip_bfloat16*)alloc(kvFull);
  } else {
    B.kbuf = (__hip_bfloat16*)alloc((size_t)cH * cNK * cD * 2);
    B.vtb  = (__hip_bfloat16*)alloc((size_t)cH * cNK * cD * 2);
  }
  size_t memBytes = (size_t)MM * cE * 2;
  used = (size_t)(wp - (char*)d_ws);
  B.precast = B.fullKV && (ws_size >= used + memBytes);
  B.membf = B.precast ? (__hip_bfloat16*)alloc(memBytes) : nullptr;

  size_t wbfTotal = 0;
  for (int i = 0; i < 8; ++i) wbfTotal += ((w_sz[i] * 2 + 255) & ~(size_t)255);
  used = (size_t)(wp - (char*)d_ws);
  bool wPre = ws_size >= used + wbfTotal;
  __hip_bfloat16* wbf[8] = {};
  if (wPre)
    for (int i = 0; i < 8; ++i) wbf[i] = (__hip_bfloat16*)alloc(w_sz[i] * 2);

  // ---- one-time prep ----
  init_t<<<(MT * cE + 255) / 256, 256, 0, stream>>>(tgt, B.t, B.tb, MT * cE);
  pack_mask_T<<<dim3(cNK / 256, cQT, cB), 256, 0, stream>>>(gmask, B.mTr);
  if (B.precast)
    cast_f32_bf16<<<(MM * cE + 255) / 256, 256, 0, stream>>>(memory, B.membf, MM * cE);
  if (wPre)
    for (int i = 0; i < 8; ++i)
      cast_f32_bf16<<<(int)((w_sz[i] + 255) / 256), 256, 0, stream>>>(w_in[i], wbf[i], (int)w_sz[i]);

  if (wPre) {
    const __hip_bfloat16* wt[8];
    for (int i = 0; i < 8; ++i) wt[i] = wbf[i];
    run_layers<__hip_bfloat16>(wt, b_in, ln1g, ln1b, ln2g, ln2b, ln3g, ln3b, B, stream);
  } else {
    run_layers<float>(w_in, b_in, ln1g, ln1b, ln2g, ln2b, ln3g, ln3b, B, stream);
  }

  final_ln_k<<<MT, 64, 0, stream>>>(B.t, lnfg, lnfb, (float*)d_out);
}

// Round 11
// 1206.826 us; speedup vs baseline: 1.0647x; 1.0647x over previous
//
#include <hip/hip_runtime.h>
#include <hip/hip_bf16.h>

// Problem dims
constexpr int cB = 8, cNQ = 300, cNK = 4096, cE = 256, cH = 8, cD = 32, cF = 2048, cL = 6;
constexpr int MT = cB * cNQ;    // 2400 rows of target stream
constexpr int MM = cB * cNK;    // 32768 rows of memory stream
constexpr int cQT = 10;         // q-tiles of 32
constexpr int cKS = 4;          // k-split
constexpr float kScale = 0.17677669529663687f;  // 32^-0.5
constexpr float kC2 = 0.25506601f;              // kScale * log2(e); exp2(s*kC2)=exp(s*kScale)

typedef __attribute__((ext_vector_type(8))) short short8_t;
typedef __attribute__((ext_vector_type(4))) short short4_t;
typedef __attribute__((ext_vector_type(4))) float float4_t;

__device__ inline short f2bf(float x) {
  __hip_bfloat16 h = __float2bfloat16(x);
  return __builtin_bit_cast(short, h);
}

// ---------------- init t (fp32 + bf16 mirror) ----------------
__global__ void init_t(const float* __restrict__ in, float* __restrict__ t,
                       __hip_bfloat16* __restrict__ tb, int n) {
  int i = blockIdx.x * 256 + threadIdx.x;
  if (i < n) { float v = in[i]; t[i] = v; tb[i] = __float2bfloat16(v); }
}
__global__ void cast_f32_bf16(const float* __restrict__ in, __hip_bfloat16* __restrict__ out, int n) {
  int i = blockIdx.x * 256 + threadIdx.x;
  if (i < n) out[i] = __float2bfloat16(in[i]);
}

// ---------------- transposed mask pack: mT[b][qt][key], bit j = mask[b][qt*32+j][key] ----
__global__ void pack_mask_T(const int* __restrict__ m, unsigned* __restrict__ mT) {
  int key = blockIdx.x * 256 + threadIdx.x;
  int qt = blockIdx.y, b = blockIdx.z;
  unsigned w = 0;
  for (int j = 0; j < 32; ++j) {
    int q = qt * 32 + j;
    unsigned bit = (q < cNQ) ? (unsigned)(m[((size_t)b * cNQ + q) * cNK + key] != 0) : 0u;
    w |= bit << j;
  }
  mT[((size_t)b * cQT + qt) * cNK + key] = w;
}

// ---------------- 64x64 MFMA GEMM ----------------
// EPI: 0 none, 1 relu, 2 scale-by-kC2 if n<256 (self QKV: scale Q half), 3 scale always.
// OMODE 0 row-major / 1 K head-major / 2 V transposed.
template<typename TA, typename TW, int EPI, int OMODE, typename TOUT>
__global__ __launch_bounds__(256) void gemm_mfma(const TA* __restrict__ A,
                                                 const TW* __restrict__ W,
                                                 const float* __restrict__ bias,
                                                 TOUT* __restrict__ C,
                                                 int M, int N, int K) {
  constexpr int LDSS = 72;
  __shared__ short As[64][LDSS];
  __shared__ short Ws[64][LDSS];
  int tid = threadIdx.x;
  int bm = blockIdx.x * 64, bn = blockIdx.y * 64;
  int lane = tid & 63, wave = tid >> 6;
  int m16 = lane & 15, quad = lane >> 4;
  int wm = (wave >> 1) * 32, wn = (wave & 1) * 32;

  int srow = tid >> 2;
  int kc = (tid & 3) * 16;
  bool aok = (bm + srow) < M;

  float4_t acc[2][2];
#pragma unroll
  for (int i = 0; i < 2; ++i)
#pragma unroll
    for (int j = 0; j < 2; ++j) acc[i][j] = (float4_t){0.f, 0.f, 0.f, 0.f};

  for (int k0 = 0; k0 < K; k0 += 64) {
    if constexpr (__hip_internal::is_same<TA, float>::value) {
      const float* src = A + (size_t)(bm + srow) * K + k0 + kc;
      short8_t p0, p1;
#pragma unroll
      for (int u = 0; u < 8; ++u) p0[u] = aok ? f2bf(src[u]) : (short)0;
#pragma unroll
      for (int u = 0; u < 8; ++u) p1[u] = aok ? f2bf(src[8 + u]) : (short)0;
      *(short8_t*)&As[srow][kc] = p0;
      *(short8_t*)&As[srow][kc + 8] = p1;
    } else {
      const TA* src = A + (size_t)(bm + srow) * K + k0 + kc;
      short8_t z = 0;
      *(short8_t*)&As[srow][kc] = aok ? *(const short8_t*)src : z;
      *(short8_t*)&As[srow][kc + 8] = aok ? *(const short8_t*)(src + 8) : z;
    }
    if constexpr (__hip_internal::is_same<TW, float>::value) {
      const float* src = W + (size_t)(bn + srow) * K + k0 + kc;
      short8_t p0, p1;
#pragma unroll
      for (int u = 0; u < 8; ++u) p0[u] = f2bf(src[u]);
#pragma unroll
      for (int u = 0; u < 8; ++u) p1[u] = f2bf(src[8 + u]);
      *(short8_t*)&Ws[srow][kc] = p0;
      *(short8_t*)&Ws[srow][kc + 8] = p1;
    } else {
      const TW* src = W + (size_t)(bn + srow) * K + k0 + kc;
      *(short8_t*)&Ws[srow][kc] = *(const short8_t*)src;
      *(short8_t*)&Ws[srow][kc + 8] = *(const short8_t*)(src + 8);
    }
    __syncthreads();
#pragma unroll
    for (int kk = 0; kk < 2; ++kk) {
      short8_t aF[2], bF[2];
#pragma unroll
      for (int i = 0; i < 2; ++i)
        aF[i] = *(const short8_t*)&As[wm + i * 16 + m16][kk * 32 + quad * 8];
#pragma unroll
      for (int j = 0; j < 2; ++j)
        bF[j] = *(const short8_t*)&Ws[wn + j * 16 + m16][kk * 32 + quad * 8];
#pragma unroll
      for (int i = 0; i < 2; ++i)
#pragma unroll
        for (int j = 0; j < 2; ++j)
          acc[i][j] = __builtin_amdgcn_mfma_f32_16x16x32_bf16(aF[i], bF[j], acc[i][j], 0, 0, 0);
    }
    __syncthreads();
  }

  if constexpr (OMODE == 2) {
#pragma unroll
    for (int i = 0; i < 2; ++i)
#pragma unroll
      for (int r = 0; r < 4; ++r) {
        int ml = wm + i * 16 + quad * 4 + r;
#pragma unroll
        for (int j = 0; j < 2; ++j) {
          int nl = wn + j * 16 + m16;
          Ws[nl][ml] = f2bf(acc[i][j][r] + bias[bn + nl]);
        }
      }
    __syncthreads();
    int nl = tid >> 2, mc = (tid & 3) * 16;
    if (bm + mc < M) {
      int n = bn + nl;
      __hip_bfloat16* dst = (__hip_bfloat16*)C +
          ((size_t)(n >> 5) * 32 + (n & 31)) * (size_t)M + bm + mc;
      *(short8_t*)dst = *(const short8_t*)&Ws[nl][mc];
      *(short8_t*)(dst + 8) = *(const short8_t*)&Ws[nl][mc + 8];
    }
  } else {
#pragma unroll
    for (int i = 0; i < 2; ++i) {
#pragma unroll
      for (int r = 0; r < 4; ++r) {
        int m = bm + wm + i * 16 + quad * 4 + r;
        if (m >= M) continue;
#pragma unroll
        for (int j = 0; j < 2; ++j) {
          int n = bn + wn + j * 16 + m16;
          float v = acc[i][j][r] + bias[n];
          if (EPI == 1) v = fmaxf(v, 0.f);
          if (EPI == 2 && n < 256) v *= kC2;
          if (EPI == 3) v *= kC2;
          if constexpr (OMODE == 1) {
            ((__hip_bfloat16*)C)[((size_t)(n >> 5) * M + m) * 32 + (n & 31)] = __float2bfloat16(v);
          } else if constexpr (__hip_internal::is_same<TOUT, float>::value) {
            C[(size_t)m * N + n] = v;
          } else {
            C[(size_t)m * N + n] = __float2bfloat16(v);
          }
        }
      }
    }
  }
}

// ---------------- 32x64 MFMA GEMM (CU-filling variant for M=2400 projections) --------
template<typename TW, int EPI, typename TOUT>
__global__ __launch_bounds__(256) void gemm32(const __hip_bfloat16* __restrict__ A,
                                              const TW* __restrict__ W,
                                              const float* __restrict__ bias,
                                              TOUT* __restrict__ C,
                                              int M, int N, int K) {
  __shared__ short As[32][72];
  __shared__ short Ws[64][72];
  int tid = threadIdx.x;
  int bm = blockIdx.x * 32, bn = blockIdx.y * 64;
  int lane = tid & 63, wave = tid >> 6;
  int m16 = lane & 15, quad = lane >> 4;
  int wn = wave * 16;

  int sa_row = tid >> 3, sa_c = (tid & 7) * 8;
  int sw_row = tid >> 2, sw_c = (tid & 3) * 16;
  bool aok = (bm + sa_row) < M;

  float4_t acc[2];
  acc[0] = (float4_t){0.f, 0.f, 0.f, 0.f};
  acc[1] = (float4_t){0.f, 0.f, 0.f, 0.f};

  for (int k0 = 0; k0 < K; k0 += 64) {
    {
      const __hip_bfloat16* src = A + (size_t)(bm + sa_row) * K + k0 + sa_c;
      short8_t z = 0;
      *(short8_t*)&As[sa_row][sa_c] = aok ? *(const short8_t*)src : z;
    }
    if constexpr (__hip_internal::is_same<TW, float>::value) {
      const float* src = W + (size_t)(bn + sw_row) * K + k0 + sw_c;
      short8_t p0, p1;
#pragma unroll
      for (int u = 0; u < 8; ++u) p0[u] = f2bf(src[u]);
#pragma unroll
      for (int u = 0; u < 8; ++u) p1[u] = f2bf(src[8 + u]);
      *(short8_t*)&Ws[sw_row][sw_c] = p0;
      *(short8_t*)&Ws[sw_row][sw_c + 8] = p1;
    } else {
      const TW* src = W + (size_t)(bn + sw_row) * K + k0 + sw_c;
      *(short8_t*)&Ws[sw_row][sw_c] = *(const short8_t*)src;
      *(short8_t*)&Ws[sw_row][sw_c + 8] = *(const short8_t*)(src + 8);
    }
    __syncthreads();
#pragma unroll
    for (int kk = 0; kk < 2; ++kk) {
      short8_t aF[2], bF;
#pragma unroll
      for (int i = 0; i < 2; ++i)
        aF[i] = *(const short8_t*)&As[i * 16 + m16][kk * 32 + quad * 8];
      bF = *(const short8_t*)&Ws[wn + m16][kk * 32 + quad * 8];
#pragma unroll
      for (int i = 0; i < 2; ++i)
        acc[i] = __builtin_amdgcn_mfma_f32_16x16x32_bf16(aF[i], bF, acc[i], 0, 0, 0);
    }
    __syncthreads();
  }

#pragma unroll
  for (int i = 0; i < 2; ++i) {
#pragma unroll
    for (int r = 0; r < 4; ++r) {
      int m = bm + i * 16 + quad * 4 + r;
      if (m >= M) continue;
      int n = bn + wn + m16;
      float v = acc[i][r] + bias[n];
      if (EPI == 1) v = fmaxf(v, 0.f);
      if (EPI == 3) v *= kC2;
      if constexpr (__hip_internal::is_same<TOUT, float>::value) {
        C[(size_t)m * N + n] = v;
      } else {
        C[(size_t)m * N + n] = __float2bfloat16(v);
      }
    }
  }
}

// ---------------- 128x128 MFMA GEMM (big grids: K/V proj, FFN-w1) ----------------
template<typename TW, int EPI, int OMODE, typename TOUT>
__global__ __launch_bounds__(256) void gemm128(const __hip_bfloat16* __restrict__ A,
                                               const TW* __restrict__ W,
                                               const float* __restrict__ bias,
                                               TOUT* __restrict__ C,
                                               int M, int N, int K) {
  __shared__ short lds[2 * 128 * 72];
  auto As = (short(*)[72])lds;
  auto Ws = (short(*)[72])(lds + 128 * 72);
  int tid = threadIdx.x;
  int bm = blockIdx.x * 128, bn = blockIdx.y * 128;
  int lane = tid & 63, wave = tid >> 6;
  int n16 = lane & 15, quad = lane >> 4;
  int wm = (wave >> 1) * 64, wn = (wave & 1) * 64;
  int srow = tid >> 1, kc = (tid & 1) * 32;
  bool aok = (bm + srow) < M;

  float4_t acc[4][4];
#pragma unroll
  for (int i = 0; i < 4; ++i)
#pragma unroll
    for (int j = 0; j < 4; ++j) acc[i][j] = (float4_t){0.f, 0.f, 0.f, 0.f};

  for (int k0 = 0; k0 < K; k0 += 64) {
    {
      const __hip_bfloat16* src = A + (size_t)(bm + srow) * K + k0 + kc;
      short8_t z = 0;
#pragma unroll
      for (int u = 0; u < 4; ++u)
        *(short8_t*)&As[srow][kc + u * 8] = aok ? *(const short8_t*)(src + u * 8) : z;
    }
    if constexpr (__hip_internal::is_same<TW, float>::value) {
      const float* src = W + (size_t)(bn + srow) * K + k0 + kc;
#pragma unroll
      for (int u = 0; u < 4; ++u) {
        short8_t p;
#pragma unroll
        for (int v = 0; v < 8; ++v) p[v] = f2bf(src[u * 8 + v]);
        *(short8_t*)&Ws[srow][kc + u * 8] = p;
      }
    } else {
      const TW* src = W + (size_t)(bn + srow) * K + k0 + kc;
#pragma unroll
      for (int u = 0; u < 4; ++u)
        *(short8_t*)&Ws[srow][kc + u * 8] = *(const short8_t*)(src + u * 8);
    }
    __syncthreads();
#pragma unroll
    for (int kk = 0; kk < 2; ++kk) {
      short8_t aF[4], bF[4];
#pragma unroll
      for (int i = 0; i < 4; ++i)
        aF[i] = *(const short8_t*)&As[wm + i * 16 + n16][kk * 32 + quad * 8];
#pragma unroll
      for (int j = 0; j < 4; ++j)
        bF[j] = *(const short8_t*)&Ws[wn + j * 16 + n16][kk * 32 + quad * 8];
#pragma unroll
      for (int i = 0; i < 4; ++i)
#pragma unroll
        for (int j = 0; j < 4; ++j)
          acc[i][j] = __builtin_amdgcn_mfma_f32_16x16x32_bf16(aF[i], bF[j], acc[i][j], 0, 0, 0);
    }
    __syncthreads();
  }

  if constexpr (OMODE == 2) {
    auto TT = (short(*)[128])lds;
#pragma unroll
    for (int i = 0; i < 4; ++i)
#pragma unroll
      for (int r = 0; r < 4; ++r) {
        int ml = wm + i * 16 + quad * 4 + r;
#pragma unroll
        for (int j = 0; j < 4; ++j) {
          int nl = wn + j * 16 + n16;
          TT[nl][ml] = f2bf(acc[i][j][r] + bias[bn + nl]);
        }
      }
    __syncthreads();
    int nl = tid >> 1, mh = (tid & 1) * 64;
    int n = bn + nl;
    __hip_bfloat16* dst = (__hip_bfloat16*)C +
        ((size_t)(n >> 5) * 32 + (n & 31)) * (size_t)M + bm + mh;
#pragma unroll
    for (int ch = 0; ch < 8; ++ch) {
      if (bm + mh + ch * 8 < M)
        *(short8_t*)(dst + ch * 8) = *(const short8_t*)&TT[nl][mh + ch * 8];
    }
  } else {
#pragma unroll
    for (int i = 0; i < 4; ++i) {
#pragma unroll
      for (int r = 0; r < 4; ++r) {
        int m = bm + wm + i * 16 + quad * 4 + r;
        if (m >= M) continue;
#pragma unroll
        for (int j = 0; j < 4; ++j) {
          int n = bn + wn + j * 16 + n16;
          float v = acc[i][j][r] + bias[n];
          if (EPI == 1) v = fmaxf(v, 0.f);
          if constexpr (OMODE == 1) {
            ((__hip_bfloat16*)C)[((size_t)(n >> 5) * M + m) * 32 + (n & 31)] = __float2bfloat16(v);
          } else if constexpr (__hip_internal::is_same<TOUT, float>::value) {
            C[(size_t)m * N + n] = v;
          } else {
            C[(size_t)m * N + n] = __float2bfloat16(v);
          }
        }
      }
    }
  }
}

// ---------------- flash attention: 4 waves per (hb, q-tile32, k-chunk) block ----------
// Q PRE-SCALED by kC2 (log2 domain); softmax numerator = raw v_exp_f32 (2^x).
// P pack via hw v_cvt_pk_bf16_f32 (RNE). Ping-pong register prefetch.
// SWZ=true: 1-D grid, XCD-aware bijective swizzle so all 10 q-tiles of one K/V slice
// land on the SAME XCD (launch ≡ slice mod 8) -> per-XCD L2 working set 32MB -> 4MB.
// SPLIT=true: write pO/pL partials (cross, cKS=4). SPLIT=false: normalize in-kernel.
template<typename TQ, bool MASKED, bool SPLIT, bool SWZ>
__global__ __launch_bounds__(256) void attn_flash(
    const TQ* __restrict__ qb, size_t strQb, size_t strQh, int qRowStr,
    const __hip_bfloat16* __restrict__ kb, size_t strKb, size_t strKh, int kRowStr,
    const __hip_bfloat16* __restrict__ vt, size_t strVb, size_t strVh, size_t strVd,
    const unsigned* __restrict__ mT, size_t strMb,
    float* __restrict__ pO, size_t pStrO,
    float* __restrict__ pL, size_t pStrL,
    __hip_bfloat16* __restrict__ outF,
    int nq, int nk, int kChunk) {
  int hb, qt, ks;
  if constexpr (SWZ) {
    // bid = xcd + 8*(qt + cQT*slice_hi); slice = slice_hi*8 + xcd; bijective for
    // grid = 8 * cQT * (slices/8). slice -> (hb, ks).
    int bid = blockIdx.x;
    int xcd = bid & 7, k = bid >> 3;
    qt = k % cQT;
    int slice = (k / cQT) * 8 + xcd;
    hb = slice >> 2;
    ks = slice & 3;
  } else {
    hb = blockIdx.x; qt = blockIdx.y; ks = blockIdx.z;
  }
  int h = hb & 7, bz = hb >> 3;
  int qbase = qt * 32;

  const TQ* q = qb + (size_t)bz * strQb + (size_t)h * strQh;
  const __hip_bfloat16* K = kb + (size_t)bz * strKb + (size_t)h * strKh;
  const __hip_bfloat16* V = vt + (size_t)bz * strVb + (size_t)h * strVh;
  const unsigned* mrow = MASKED ? (mT + (size_t)bz * strMb + (size_t)qt * cNK) : nullptr;

  int tid = threadIdx.x;
  int lane = tid & 63, wave = tid >> 6;
  int n16 = lane & 15, quad = lane >> 4;

  // reduction buffers; per-wave P-staging (sP, 4*32*40 shorts = 10240 B) aliases redO
  __shared__ float redO[4][32][33];   // 16896 B
  __shared__ float redL[4][32];       //   512 B
  short* sPw = (short*)&redO[0][0][0] + wave * (32 * 40);

  short8_t qf[2];
#pragma unroll
  for (int qi = 0; qi < 2; ++qi) {
    qf[qi] = 0;
    int qr = qbase + qi * 16 + n16;
    if (qr < nq) {
      const TQ* qp = q + (size_t)qr * qRowStr + quad * 8;
      if constexpr (__hip_internal::is_same<TQ, float>::value) {
#pragma unroll
        for (int j = 0; j < 8; ++j) qf[qi][j] = f2bf(qp[j]);
      } else {
        qf[qi] = *(const short8_t*)qp;
      }
    }
  }
  short8_t ones;
#pragma unroll
  for (int j = 0; j < 8; ++j) ones[j] = f2bf(1.0f);

  float4_t accO[2][2], accL[2];
#pragma unroll
  for (int qi = 0; qi < 2; ++qi) {
    accL[qi] = (float4_t){0.f, 0.f, 0.f, 0.f};
#pragma unroll
    for (int di = 0; di < 2; ++di) accO[qi][di] = (float4_t){0.f, 0.f, 0.f, 0.f};
  }
  float4_t zero4 = {0.f, 0.f, 0.f, 0.f};

  int kpad = (nk + 31) & ~31;
  int kbeg = ks * kChunk + wave * 32;
  int kend = ks * kChunk + kChunk;
  if (kend > kpad) kend = kpad;

  // ping-pong register sets (A/B), loaded in place — no per-iter copies
  short8_t ka0, ka1, va0, va1, kb0, kb1, vb0, vb1;
  unsigned wa0 = 0, wa1 = 0, wb0 = 0, wb1 = 0;
  float oa0 = 1.f, oa1 = 1.f, ob0 = 1.f, ob1 = 1.f;

#define ATTN_LOAD(KF0, KF1, VF0, VF1, W0, W1, O0, O1, KO)                          \
  {                                                                                \
    int k0_ = (KO) + 2 * n16;                                                      \
    if (MASKED) {                                                                  \
      uint2 mw_ = *(const uint2*)(mrow + k0_);                                     \
      W0 = mw_.x; W1 = mw_.y;                                                      \
    } else {                                                                       \
      O0 = (k0_ < nk) ? 1.f : 0.f;                                                 \
      O1 = (k0_ + 1 < nk) ? 1.f : 0.f;                                             \
    }                                                                              \
    KF0 = *(const short8_t*)(K + (size_t)k0_ * kRowStr + quad * 8);                \
    KF1 = *(const short8_t*)(K + (size_t)(k0_ + 1) * kRowStr + quad * 8);          \
    VF0 = *(const short8_t*)(V + (size_t)n16 * strVd + (KO) + quad * 8);           \
    VF1 = *(const short8_t*)(V + (size_t)(16 + n16) * strVd + (KO) + quad * 8);    \
  }

#define ATTN_COMPUTE(CK0, CK1, CV0, CV1, CW0, CW1, CO0, CO1)                       \
  {                                                                                \
    float4_t s00 = __builtin_amdgcn_mfma_f32_16x16x32_bf16(qf[0], CK0, zero4, 0, 0, 0); \
    float4_t s01 = __builtin_amdgcn_mfma_f32_16x16x32_bf16(qf[0], CK1, zero4, 0, 0, 0); \
    float4_t s10 = __builtin_amdgcn_mfma_f32_16x16x32_bf16(qf[1], CK0, zero4, 0, 0, 0); \
    float4_t s11 = __builtin_amdgcn_mfma_f32_16x16x32_bf16(qf[1], CK1, zero4, 0, 0, 0); \
    _Pragma("unroll")                                                              \
    for (int qi = 0; qi < 2; ++qi) {                                               \
      const float4_t& sa = qi ? s10 : s00;                                         \
      const float4_t& sb = qi ? s11 : s01;                                         \
      _Pragma("unroll")                                                            \
      for (int r = 0; r < 4; ++r) {                                                \
        int row_ = qi * 16 + quad * 4 + r;                                         \
        float e0_, e1_;                                                            \
        asm("v_exp_f32 %0, %1" : "=v"(e0_) : "v"(sa[r]));                          \
        asm("v_exp_f32 %0, %1" : "=v"(e1_) : "v"(sb[r]));                          \
        float m0_, m1_;                                                            \
        if (MASKED) {                                                              \
          m0_ = (float)((CW0 >> row_) & 1u);                                       \
          m1_ = (float)((CW1 >> row_) & 1u);                                       \
        } else {                                                                   \
          m0_ = CO0; m1_ = CO1;                                                    \
        }                                                                          \
        e0_ *= m0_; e1_ *= m1_;                                                    \
        unsigned pw_;                                                              \
        asm("v_cvt_pk_bf16_f32 %0, %1, %2" : "=v"(pw_) : "v"(e0_), "v"(e1_));      \
        *(unsigned*)&sPw[row_ * 40 + 2 * n16] = pw_;                               \
      }                                                                            \
    }                                                                              \
    _Pragma("unroll")                                                              \
    for (int qi = 0; qi < 2; ++qi) {                                               \
      short8_t pf = *(const short8_t*)&sPw[(qi * 16 + n16) * 40 + quad * 8];       \
      accO[qi][0] = __builtin_amdgcn_mfma_f32_16x16x32_bf16(pf, CV0, accO[qi][0], 0, 0, 0); \
      accO[qi][1] = __builtin_amdgcn_mfma_f32_16x16x32_bf16(pf, CV1, accO[qi][1], 0, 0, 0); \
      accL[qi]    = __builtin_amdgcn_mfma_f32_16x16x32_bf16(pf, ones, accL[qi], 0, 0, 0);   \
    }                                                                              \
  }

  int ko = kbeg;
  if (ko < kend) {
    ATTN_LOAD(ka0, ka1, va0, va1, wa0, wa1, oa0, oa1, ko);
    while (true) {
      int nx = ko + 128;
      if (nx < kend) ATTN_LOAD(kb0, kb1, vb0, vb1, wb0, wb1, ob0, ob1, nx);
      ATTN_COMPUTE(ka0, ka1, va0, va1, wa0, wa1, oa0, oa1);
      ko = nx;
      if (ko >= kend) break;
      nx = ko + 128;
      if (nx < kend) ATTN_LOAD(ka0, ka1, va0, va1, wa0, wa1, oa0, oa1, nx);
      ATTN_COMPUTE(kb0, kb1, vb0, vb1, wb0, wb1, ob0, ob1);
      ko = nx;
      if (ko >= kend) break;
    }
  }
#undef ATTN_LOAD
#undef ATTN_COMPUTE

  // all waves done with their sP region before it is overwritten by redO
  __syncthreads();
#pragma unroll
  for (int qi = 0; qi < 2; ++qi) {
#pragma unroll
    for (int r = 0; r < 4; ++r) {
      int row = qi * 16 + quad * 4 + r;
#pragma unroll
      for (int di = 0; di < 2; ++di)
        redO[wave][row][di * 16 + n16] = accO[qi][di][r];
      if (n16 == 0) redL[wave][row] = accL[qi][r];
    }
  }
  __syncthreads();

  int row = tid >> 3, c0 = (tid & 7) * 4;
  if constexpr (SPLIT) {
    size_t oBase = (size_t)ks * pStrO + (size_t)(bz * cNQ) * 256 + h * 32;
    if (qbase + row < nq) {
      float4_t o;
#pragma unroll
      for (int u = 0; u < 4; ++u)
        o[u] = redO[0][row][c0 + u] + redO[1][row][c0 + u] +
               redO[2][row][c0 + u] + redO[3][row][c0 + u];
      *(float4_t*)&pO[oBase + (size_t)(qbase + row) * 256 + c0] = o;
    }
    if (tid < 32 && qbase + tid < nq) {
      float l = redL[0][tid] + redL[1][tid] + redL[2][tid] + redL[3][tid];
      pL[(size_t)ks * pStrL + (size_t)hb * 320 + qbase + tid] = l;
    }
  } else {
    if (qbase + row < nq) {
      float l = redL[0][row] + redL[1][row] + redL[2][row] + redL[3][row];
      float inv = 1.f / l;
      float o[4];
#pragma unroll
      for (int u = 0; u < 4; ++u)
        o[u] = (redO[0][row][c0 + u] + redO[1][row][c0 + u] +
                redO[2][row][c0 + u] + redO[3][row][c0 + u]) * inv;
      short4_t res = {f2bf(o[0]), f2bf(o[1]), f2bf(o[2]), f2bf(o[3])};
      *(short4_t*)&outF[(size_t)(bz * cNQ + qbase + row) * 256 + h * 32 + c0] = res;
    }
  }
}

// ---------------- merge k-split partials -> bf16 ----------------
__global__ __launch_bounds__(64) void attn_merge(const float* __restrict__ pO,
                                                 const float* __restrict__ pL,
                                                 __hip_bfloat16* __restrict__ out) {
  int row = blockIdx.x;
  int lane = threadIdx.x;
  int c0 = lane * 4;
  int bz = row / cNQ, qq = row - bz * cNQ;
  int h = c0 >> 5;
  float l = 0.f;
#pragma unroll
  for (int ks = 0; ks < cKS; ++ks)
    l += pL[(size_t)ks * (64 * 320) + (size_t)(bz * 8 + h) * 320 + qq];
  float inv = 1.f / l;
  float o[4] = {0.f, 0.f, 0.f, 0.f};
#pragma unroll
  for (int ks = 0; ks < cKS; ++ks) {
    const float4_t v = *(const float4_t*)&pO[(size_t)ks * (MT * 256) + (size_t)row * 256 + c0];
#pragma unroll
    for (int u = 0; u < 4; ++u) o[u] += v[u];
  }
  short4_t res = {f2bf(o[0] * inv), f2bf(o[1] * inv), f2bf(o[2] * inv), f2bf(o[3] * inv)};
  *(short4_t*)&out[(size_t)row * 256 + c0] = res;
}

// ---------------- residual + LayerNorm (fp32 t + bf16 mirror), one wave per row ------
__global__ __launch_bounds__(64) void add_ln_k(float* __restrict__ t,
                                               __hip_bfloat16* __restrict__ tb,
                                               const float* __restrict__ delta,
                                               const float* __restrict__ g,
                                               const float* __restrict__ bb) {
  int r = blockIdx.x, lane = threadIdx.x;
  size_t base = (size_t)r * cE + lane * 4;
  float x[4];
  float s = 0.f;
#pragma unroll
  for (int i = 0; i < 4; ++i) { x[i] = t[base + i] + delta[base + i]; s += x[i]; }
  for (int off = 32; off; off >>= 1) s += __shfl_xor(s, off);
  float mean = s * (1.f / cE);
  float v = 0.f;
#pragma unroll
  for (int i = 0; i < 4; ++i) { float dd = x[i] - mean; v += dd * dd; }
  for (int off = 32; off; off >>= 1) v += __shfl_xor(v, off);
  float rstd = rsqrtf(v * (1.f / cE) + 1e-5f);
  float y[4];
#pragma unroll
  for (int i = 0; i < 4; ++i) {
    y[i] = (x[i] - mean) * rstd * g[lane * 4 + i] + bb[lane * 4 + i];
    t[base + i] = y[i];
  }
  short4_t pb = {f2bf(y[0]), f2bf(y[1]), f2bf(y[2]), f2bf(y[3])};
  *(short4_t*)&tb[base] = pb;
}

// ---------------- final LayerNorm -> fp32 out ----------------
__global__ __launch_bounds__(64) void final_ln_k(const float* __restrict__ t,
                                                 const float* __restrict__ g,
                                                 const float* __restrict__ bb,
                                                 float* __restrict__ out) {
  int r = blockIdx.x, lane = threadIdx.x;
  size_t base = (size_t)r * cE + lane * 4;
  float x[4];
  float s = 0.f;
#pragma unroll
  for (int i = 0; i < 4; ++i) { x[i] = t[base + i]; s += x[i]; }
  for (int off = 32; off; off >>= 1) s += __shfl_xor(s, off);
  float mean = s * (1.f / cE);
  float v = 0.f;
#pragma unroll
  for (int i = 0; i < 4; ++i) { float dd = x[i] - mean; v += dd * dd; }
  for (int off = 32; off; off >>= 1) v += __shfl_xor(v, off);
  float rstd = rsqrtf(v * (1.f / cE) + 1e-5f);
#pragma unroll
  for (int i = 0; i < 4; ++i)
    out[base + i] = (x[i] - mean) * rstd * g[lane * 4 + i] + bb[lane * 4 + i];
}

// ---------------- pipeline (templated on weight dtype TW) ----------------
struct Bufs {
  float *t, *s1, *s2, *pO, *pL;
  __hip_bfloat16 *tb, *big2, *vtq, *saOut, *s2b, *qbf, *ffnh, *kbuf, *vtb, *membf;
  unsigned* mTr;
  const float* memory;
  bool fullKV, precast;
};

template<typename TW>
static void run_layers(const TW* const* wt, const float* const* bs,
                       const float* ln1g, const float* ln1b,
                       const float* ln2g, const float* ln2b,
                       const float* ln3g, const float* ln3b,
                       Bufs B, hipStream_t stream) {
  const size_t pStrO = (size_t)MT * 256, pStrL = 64 * 320;
  for (int l = 0; l < cL; ++l) {
    const TW* wqkv = wt[0] + (size_t)l * 3 * cE * cE;  const float* bqkv = bs[0] + (size_t)l * 3 * cE;
    const TW* wo   = wt[1] + (size_t)l * cE * cE;      const float* bo   = bs[1] + (size_t)l * cE;
    const TW* wq   = wt[2] + (size_t)l * cE * cE;      const float* bq   = bs[2] + (size_t)l * cE;
    const TW* wk   = wt[3] + (size_t)l * cE * cE;      const float* bk   = bs[3] + (size_t)l * cE;
    const TW* wv   = wt[4] + (size_t)l * cE * cE;      const float* bv   = bs[4] + (size_t)l * cE;
    const TW* wco  = wt[5] + (size_t)l * cE * cE;      const float* bco  = bs[5] + (size_t)l * cE;
    const TW* w1   = wt[6] + (size_t)l * cF * cE;      const float* b1   = bs[6] + (size_t)l * cF;
    const TW* w2   = wt[7] + (size_t)l * cE * cF;      const float* b2   = bs[7] + (size_t)l * cE;

    // 1) self Q|K -> big2 (bf16, stride 512); Q half (n<256) pre-scaled by kC2
    gemm_mfma<__hip_bfloat16, TW, 2, 0, __hip_bfloat16><<<dim3(38, 8), 256, 0, stream>>>(
        B.tb, wqkv, bqkv, B.big2, MT, 512, cE);
    // 2) self V^T -> vtq [h][dim][2400]
    gemm_mfma<__hip_bfloat16, TW, 0, 2, __hip_bfloat16><<<dim3(38, 4), 256, 0, stream>>>(
        B.tb, wqkv + (size_t)512 * cE, bqkv + 512, B.vtq, MT, cE, cE);
    // 3) self flash, no k-split; normalized bf16 out -> saOut. Merge eliminated.
    attn_flash<__hip_bfloat16, false, false, false><<<dim3(64, cQT, 1), 256, 0, stream>>>(
        B.big2, (size_t)cNQ * 512, 32, 512,
        B.big2 + 256, (size_t)cNQ * 512, 32, 512,
        B.vtq, 300, (size_t)cD * MT, MT,
        nullptr, 0,
        B.pO, pStrO, B.pL, pStrL, B.saOut, cNQ, cNQ, 320);
    // 4) sa out proj -> s2 (fp32)
    gemm32<TW, 0, float><<<dim3(75, 4), 256, 0, stream>>>(
        B.saOut, wo, bo, B.s2, MT, cE, cE);
    add_ln_k<<<MT, 64, 0, stream>>>(B.t, B.tb, B.s2, ln1g + (size_t)l * cE, ln1b + (size_t)l * cE);
    // 5) q proj -> qbf (pre-scaled by kC2)
    gemm32<TW, 3, __hip_bfloat16><<<dim3(75, 4), 256, 0, stream>>>(
        B.tb, wq, bq, B.qbf, MT, cE, cE);
    // 6) K/V projections + cross flash (XCD-swizzled 1-D grid)
    if (B.fullKV && B.precast) {
      gemm128<TW, 0, 1, __hip_bfloat16><<<dim3(256, 2), 256, 0, stream>>>(
          B.membf, wk, bk, B.kbuf, MM, cE, cE);
      gemm128<TW, 0, 2, __hip_bfloat16><<<dim3(256, 2), 256, 0, stream>>>(
          B.membf, wv, bv, B.vtb, MM, cE, cE);
      attn_flash<__hip_bfloat16, true, true, true><<<dim3(64 * cQT * cKS), 256, 0, stream>>>(
          B.qbf, (size_t)cNQ * cE, 32, cE,
          B.kbuf, (size_t)cNK * cD, (size_t)MM * cD, cD,
          B.vtb, (size_t)cNK, (size_t)cD * MM, MM,
          B.mTr, (size_t)cQT * cNK,
          B.pO, pStrO, B.pL, pStrL, nullptr, cNQ, cNK, 1024);
      attn_merge<<<MT, 64, 0, stream>>>(B.pO, B.pL, B.s2b);
    } else {
      for (int b = 0; b < cB; ++b) {
        const float* memb = B.memory + (size_t)b * cNK * cE;
        gemm_mfma<float, TW, 0, 1, __hip_bfloat16><<<dim3(64, 4), 256, 0, stream>>>(
            memb, wk, bk, B.kbuf, cNK, cE, cE);
        gemm_mfma<float, TW, 0, 2, __hip_bfloat16><<<dim3(64, 4), 256, 0, stream>>>(
            memb, wv, bv, B.vtb, cNK, cE, cE);
        attn_flash<__hip_bfloat16, true, true, false><<<dim3(8, cQT, cKS), 256, 0, stream>>>(
            B.qbf + (size_t)b * cNQ * cE, 0, 32, cE,
            B.kbuf, 0, (size_t)cNK * cD, cD,
            B.vtb, 0, (size_t)cD * cNK, cNK,
            B.mTr + (size_t)b * cQT * cNK, 0,
            B.pO + (size_t)b * cNQ * 256, pStrO, B.pL + (size_t)b * 8 * 320, pStrL,
            nullptr, cNQ, cNK, 1024);
      }
      attn_merge<<<MT, 64, 0, stream>>>(B.pO, B.pL, B.s2b);
    }
    // 7) ca out proj -> s1 (fp32)
    gemm32<TW, 0, float><<<dim3(75, 4), 256, 0, stream>>>(
        B.s2b, wco, bco, B.s1, MT, cE, cE);
    add_ln_k<<<MT, 64, 0, stream>>>(B.t, B.tb, B.s1, ln2g + (size_t)l * cE, ln2b + (size_t)l * cE);
    // 8) FFN
    gemm128<TW, 1, 0, __hip_bfloat16><<<dim3(19, 16), 256, 0, stream>>>(
        B.tb, w1, b1, B.ffnh, MT, cF, cE);
    gemm32<TW, 0, float><<<dim3(75, 4), 256, 0, stream>>>(
        B.ffnh, w2, b2, B.s1, MT, cE, cF);
    add_ln_k<<<MT, 64, 0, stream>>>(B.t, B.tb, B.s1, ln3g + (size_t)l * cE, ln3b + (size_t)l * cE);
  }
}

extern "C" void kernel_launch(void* const* d_in, const int* in_sizes, int n_in,
                              void* d_out, int out_size, void* d_ws, size_t ws_size,
                              hipStream_t stream) {
  (void)in_sizes; (void)n_in; (void)out_size;
  const float* tgt    = (const float*)d_in[0];
  const float* memory = (const float*)d_in[1];
  const int*   gmask  = (const int*)d_in[2];
  const float* w_in[8]  = {(const float*)d_in[3], (const float*)d_in[5], (const float*)d_in[7],
                           (const float*)d_in[9], (const float*)d_in[11], (const float*)d_in[13],
                           (const float*)d_in[15], (const float*)d_in[17]};
  const float* b_in[8]  = {(const float*)d_in[4], (const float*)d_in[6], (const float*)d_in[8],
                           (const float*)d_in[10], (const float*)d_in[12], (const float*)d_in[14],
                           (const float*)d_in[16], (const float*)d_in[18]};
  const size_t w_sz[8]  = {(size_t)cL*3*cE*cE, (size_t)cL*cE*cE, (size_t)cL*cE*cE,
                           (size_t)cL*cE*cE, (size_t)cL*cE*cE, (size_t)cL*cE*cE,
                           (size_t)cL*cF*cE, (size_t)cL*cE*cF};
  const float* ln1g = (const float*)d_in[19], *ln1b = (const float*)d_in[20];
  const float* ln2g = (const float*)d_in[21], *ln2b = (const float*)d_in[22];
  const float* ln3g = (const float*)d_in[23], *ln3b = (const float*)d_in[24];
  const float* lnfg = (const float*)d_in[25], *lnfb = (const float*)d_in[26];

  // ---- workspace allocator (256B aligned), ordered by value ----
  char* wp = (char*)d_ws;
  auto alloc = [&](size_t bytes) { void* p = wp; wp += (bytes + 255) & ~(size_t)255; return p; };

  Bufs B;
  B.memory = memory;
  B.t  = (float*)alloc((size_t)MT * cE * 4);
  B.s1 = (float*)alloc((size_t)MT * cE * 4);
  B.s2 = (float*)alloc((size_t)MT * cE * 4);
  B.tb = (__hip_bfloat16*)alloc((size_t)MT * cE * 2);
  B.big2 = (__hip_bfloat16*)alloc((size_t)MT * 512 * 2);
  B.vtq  = (__hip_bfloat16*)alloc((size_t)cH * cD * MT * 2);
  B.mTr = (unsigned*)alloc((size_t)cB * cQT * cNK * 4);
  B.pO = (float*)alloc((size_t)cKS * MT * 256 * 4);
  B.pL = (float*)alloc((size_t)cKS * 64 * 320 * 4);
  B.saOut = (__hip_bfloat16*)B.pO;                 // self-attn bf16 out (pO free then)
  B.s2b = B.big2 + (size_t)MT * 256;               // alias (big2 upper half, free after self)
  B.qbf = (__hip_bfloat16*)B.s1;                   // alias (s1 fp32 written later)
  B.ffnh = (__hip_bfloat16*)B.pO;                  // alias (pO free during FFN)

  size_t kvFull = (size_t)cH * MM * cD * 2;        // 16.78 MB each
  size_t used = (size_t)(wp - (char*)d_ws);
  B.fullKV = ws_size >= used + 2 * kvFull;
  if (B.fullKV) {
    B.kbuf = (__hip_bfloat16*)alloc(kvFull);
    B.vtb  = (__hip_bfloat16*)alloc(kvFull);
  } else {
    B.kbuf = (__hip_bfloat16*)alloc((size_t)cH * cNK * cD * 2);
    B.vtb  = (__hip_bfloat16*)alloc((size_t)cH * cNK * cD * 2);
  }
  size_t memBytes = (size_t)MM * cE * 2;
  used = (size_t)(wp - (char*)d_ws);
  B.precast = B.fullKV && (ws_size >= used + memBytes);
  B.membf = B.precast ? (__hip_bfloat16*)alloc(memBytes) : nullptr;

  size_t wbfTotal = 0;
  for (int i = 0; i < 8; ++i) wbfTotal += ((w_sz[i] * 2 + 255) & ~(size_t)255);
  used = (size_t)(wp - (char*)d_ws);
  bool wPre = ws_size >= used + wbfTotal;
  __hip_bfloat16* wbf[8] = {};
  if (wPre)
    for (int i = 0; i < 8; ++i) wbf[i] = (__hip_bfloat16*)alloc(w_sz[i] * 2);

  // ---- one-time prep ----
  init_t<<<(MT * cE + 255) / 256, 256, 0, stream>>>(tgt, B.t, B.tb, MT * cE);
  pack_mask_T<<<dim3(cNK / 256, cQT, cB), 256, 0, stream>>>(gmask, B.mTr);
  if (B.precast)
    cast_f32_bf16<<<(MM * cE + 255) / 256, 256, 0, stream>>>(memory, B.membf, MM * cE);
  if (wPre)
    for (int i = 0; i < 8; ++i)
      cast_f32_bf16<<<(int)((w_sz[i] + 255) / 256), 256, 0, stream>>>(w_in[i], wbf[i], (int)w_sz[i]);

  if (wPre) {
    const __hip_bfloat16* wt[8];
    for (int i = 0; i < 8; ++i) wt[i] = wbf[i];
    run_layers<__hip_bfloat16>(wt, b_in, ln1g, ln1b, ln2g, ln2b, ln3g, ln3b, B, stream);
  } else {
    run_layers<float>(w_in, b_in, ln1g, ln1b, ln2g, ln2b, ln3g, ln3b, B, stream);
  }

  final_ln_k<<<MT, 64, 0, stream>>>(B.t, lnfg, lnfb, (float*)d_out);
}